// Round 4
// baseline (385.251 us; speedup 1.0000x reference)
//
#include <hip/hip_runtime.h>
#include <hip/hip_bf16.h>

#define RMAXF 2.0f
#define PI_F 3.14159265358979f

// ---------------------------------------------------------------------------
// Kernel 1: per-atom parameter precompute.
//   par[a] = { A = |rep_prefactor[Z[a]]| , S = 1/|rep_scale[Z[a]]| }
// exponent identity: (R_i+R_j)/(R_i*R_j) = S_i + S_j  (removes rcp per edge)
// 200K atoms -> 1.6 MB, L2-resident per XCD.
// ---------------------------------------------------------------------------
__global__ __launch_bounds__(256) void build_params(
    const int*   __restrict__ Z,
    const float* __restrict__ rep_scale,
    const float* __restrict__ rep_prefactor,
    float2*      __restrict__ par,
    int n_atoms)
{
    int a = blockIdx.x * blockDim.x + threadIdx.x;
    if (a < n_atoms) {
        int z = Z[a];
        float A = fabsf(rep_prefactor[z]);          // 476B tables: L1-resident
        float S = __builtin_amdgcn_rcpf(fabsf(rep_scale[z]));
        par[a] = make_float2(A, S);
    }
}

// ---------------------------------------------------------------------------
// Kernel 2: one quad (4 edges) per thread, no loop. All VMEM (3 float4 dr,
// 2 int4 idx, 8 float2 param gathers) issue before any dependent use ->
// max memory-level parallelism per wave; 36-60 VGPR keeps 8 waves/SIMD.
// Dependency chain is now idx -> par gather -> compute (2 levels, no LDS).
// ---------------------------------------------------------------------------
__global__ __launch_bounds__(256) void edge_kernel(
    const float4* __restrict__ dr4,
    const int4*   __restrict__ idx_i4,
    const int4*   __restrict__ idx_j4,
    const float2* __restrict__ par,
    float*        __restrict__ out,
    int n_quads, int n_edges)
{
    int q = blockIdx.x * blockDim.x + threadIdx.x;
    float acc = 0.0f;

    if (q < n_quads) {
        float4 a = dr4[3 * q + 0];
        float4 b = dr4[3 * q + 1];
        float4 c = dr4[3 * q + 2];
        int4 i4 = idx_i4[q];
        int4 j4 = idx_j4[q];

        int ii[4] = { i4.x, i4.y, i4.z, i4.w };
        int jj[4] = { j4.x, j4.y, j4.z, j4.w };

        // hoist all 8 gathers so they are in flight together
        float2 pi_[4], pj_[4];
        #pragma unroll
        for (int k = 0; k < 4; ++k) { pi_[k] = par[ii[k]]; pj_[k] = par[jj[k]]; }

        float d2[4];
        d2[0] = a.x * a.x + a.y * a.y + a.z * a.z;
        d2[1] = a.w * a.w + b.x * b.x + b.y * b.y;
        d2[2] = b.z * b.z + b.w * b.w + c.x * c.x;
        d2[3] = c.y * c.y + c.z * c.z + c.w * c.w;

        #pragma unroll
        for (int k = 0; k < 4; ++k) {
            // clip(sqrt(d2), 0.02, 2) == sqrt(clip(d2, 4e-4, 4))
            float d2c = fminf(fmaxf(d2[k], 4.0e-4f), 4.0f);
            float dr  = __builtin_amdgcn_sqrtf(d2c);
            // 0.5*(cos(pi*dr/2)+1) == cos^2(pi*dr/4)
            float cv  = __cosf((0.25f * PI_F) * dr);
            float e   = __expf(-dr * (pi_[k].y + pj_[k].y));
            float f   = pi_[k].x * pj_[k].x * e * __builtin_amdgcn_rcpf(d2c) * cv * cv;
            acc += (ii[k] != jj[k]) ? f : 0.0f;
        }
    }

    // tail (n_edges % 4) — empty for 12.8M edges, kept for generality
    if (blockIdx.x == gridDim.x - 1 && threadIdx.x == 0) {
        const float* drf = (const float*)dr4;
        const int* idx_i = (const int*)idx_i4;
        const int* idx_j = (const int*)idx_j4;
        for (int e = n_quads * 4; e < n_edges; ++e) {
            float x = drf[3 * e + 0], y = drf[3 * e + 1], z = drf[3 * e + 2];
            float d2c = fminf(fmaxf(x * x + y * y + z * z, 4.0e-4f), 4.0f);
            float dr  = sqrtf(d2c);
            float cv  = __cosf((0.25f * PI_F) * dr);
            int i = idx_i[e], j = idx_j[e];
            float2 pi_ = par[i], pj_ = par[j];
            float f = pi_.x * pj_.x * __expf(-dr * (pi_.y + pj_.y)) / d2c * cv * cv;
            if (i != j) acc += f;
        }
    }

    // wave64 shuffle reduce -> block reduce -> one atomic per block
    #pragma unroll
    for (int off = 32; off > 0; off >>= 1)
        acc += __shfl_down(acc, off, 64);

    __shared__ float wsum[4];
    int lane = threadIdx.x & 63;
    int wid  = threadIdx.x >> 6;
    if (lane == 0) wsum[wid] = acc;
    __syncthreads();
    if (threadIdx.x == 0)
        atomicAdd(out, wsum[0] + wsum[1] + wsum[2] + wsum[3]);
}

// ---------------------------------------------------------------------------
// Fallback (ws too small or unaligned idx_j): previous LDS-table kernel,
// grid-stride scalar per edge. Correct but slower; not expected to be used.
// ---------------------------------------------------------------------------
__global__ __launch_bounds__(256) void edge_kernel_fallback(
    const float* __restrict__ drf,
    const int*   __restrict__ idx_i,
    const int*   __restrict__ idx_j,
    const int*   __restrict__ Z,
    const float* __restrict__ rep_scale,
    const float* __restrict__ rep_prefactor,
    float*       __restrict__ out,
    int n_edges)
{
    __shared__ float2 tab[128];
    for (int t = threadIdx.x; t < 119; t += blockDim.x)
        tab[t] = make_float2(fabsf(rep_prefactor[t]),
                             __builtin_amdgcn_rcpf(fabsf(rep_scale[t])));
    __syncthreads();

    float acc = 0.0f;
    const int stride = gridDim.x * blockDim.x;
    for (int e = blockIdx.x * blockDim.x + threadIdx.x; e < n_edges; e += stride) {
        float x = drf[3 * e + 0], y = drf[3 * e + 1], z = drf[3 * e + 2];
        float d2c = fminf(fmaxf(x * x + y * y + z * z, 4.0e-4f), 4.0f);
        float dr  = __builtin_amdgcn_sqrtf(d2c);
        float cv  = __cosf((0.25f * PI_F) * dr);
        int i = idx_i[e], j = idx_j[e];
        float2 pi_ = tab[Z[i]], pj_ = tab[Z[j]];
        float f = pi_.x * pj_.x * __expf(-dr * (pi_.y + pj_.y))
                  * __builtin_amdgcn_rcpf(d2c) * cv * cv;
        acc += (i != j) ? f : 0.0f;
    }

    #pragma unroll
    for (int off = 32; off > 0; off >>= 1)
        acc += __shfl_down(acc, off, 64);
    __shared__ float wsum[4];
    int lane = threadIdx.x & 63;
    int wid  = threadIdx.x >> 6;
    if (lane == 0) wsum[wid] = acc;
    __syncthreads();
    if (threadIdx.x == 0)
        atomicAdd(out, wsum[0] + wsum[1] + wsum[2] + wsum[3]);
}

extern "C" void kernel_launch(void* const* d_in, const int* in_sizes, int n_in,
                              void* d_out, int out_size, void* d_ws, size_t ws_size,
                              hipStream_t stream) {
    // inputs: 0=R, 1=dr_vec, 2=Z, 3=idx, 4=box, 5=properties, 6=rep_scale, 7=rep_prefactor
    const float* dr_vec        = (const float*)d_in[1];
    const int*   Z             = (const int*)d_in[2];
    const int*   idx           = (const int*)d_in[3];
    const float* rep_scale     = (const float*)d_in[6];
    const float* rep_prefactor = (const float*)d_in[7];
    float* out = (float*)d_out;

    const int n_atoms = in_sizes[2];
    const int n_edges = in_sizes[3] / 2;       // idx is (2, N_EDGES)
    const int n_quads = n_edges / 4;
    const int* idx_i = idx;
    const int* idx_j = idx + n_edges;

    // d_out poisoned 0xAA before every replay — zero on-stream
    hipMemsetAsync(d_out, 0, sizeof(float), stream);

    const size_t par_bytes = (size_t)n_atoms * sizeof(float2);
    const bool aligned = ((n_edges & 3) == 0);   // int4 cast of idx_j needs 16B align

    if (ws_size >= par_bytes && aligned) {
        float2* par = (float2*)d_ws;             // d_ws poisoned too — rebuilt every call
        build_params<<<(n_atoms + 255) / 256, 256, 0, stream>>>(
            Z, rep_scale, rep_prefactor, par, n_atoms);
        edge_kernel<<<(n_quads + 255) / 256, 256, 0, stream>>>(
            (const float4*)dr_vec, (const int4*)idx_i, (const int4*)idx_j,
            par, out, n_quads, n_edges);
    } else {
        int blocks = (n_edges + 255) / 256;
        if (blocks > 4096) blocks = 4096;
        edge_kernel_fallback<<<blocks, 256, 0, stream>>>(
            dr_vec, idx_i, idx_j, Z, rep_scale, rep_prefactor, out, n_edges);
    }
}